// Round 1
// baseline (1464.431 us; speedup 1.0000x reference)
//
#include <hip/hip_runtime.h>
#include <cstdint>

#define IN_F 4096
#define OUT_F 4096
#define M_TOT 8192     // BATCH*SEQ = 4*2048
#define TOTAL_R 63

typedef __attribute__((ext_vector_type(8))) short bf16x8;
typedef __attribute__((ext_vector_type(4))) float f32x4;
typedef __attribute__((ext_vector_type(8))) unsigned short u16x8;
typedef __attribute__((ext_vector_type(4))) unsigned short u16x4;

__device__ __forceinline__ uint16_t f2bf_rn(float f) {
  uint32_t u = __float_as_uint(f);
  u += 0x7fffu + ((u >> 16) & 1u);   // round-to-nearest-even
  return (uint16_t)(u >> 16);
}
__device__ __forceinline__ float bf2f(uint16_t b) {
  return __uint_as_float(((uint32_t)b) << 16);
}

__device__ __forceinline__ void gload_lds16(const void* g, void* l) {
  __builtin_amdgcn_global_load_lds((const __attribute__((address_space(1))) void*)g,
                                   (__attribute__((address_space(3))) void*)l,
                                   16, 0, 0);
}

__device__ __forceinline__ int seg_of(int r) {
  // RANKS = [32,16,8,4,2,1] -> prefix 32,48,56,60,62,63
  return (r < 32) ? 0 : (r < 48) ? 1 : (r < 56) ? 2 : (r < 60) ? 3 : (r < 62) ? 4 : 5;
}

// ---------- split x (f32) into hi/lo bf16 ----------
__global__ void split_x_kernel(const float* __restrict__ x,
                               uint16_t* __restrict__ xh,
                               uint16_t* __restrict__ xl) {
  size_t i = (size_t)blockIdx.x * blockDim.x + threadIdx.x;  // one per 8 floats
  const float4* xv = (const float4*)x;
  float4 v0 = xv[2 * i];
  float4 v1 = xv[2 * i + 1];
  float v[8] = {v0.x, v0.y, v0.z, v0.w, v1.x, v1.y, v1.z, v1.w};
  u16x8 h, lo;
#pragma unroll
  for (int k = 0; k < 8; ++k) {
    uint16_t hb = f2bf_rn(v[k]);
    h[k] = hb;
    lo[k] = f2bf_rn(v[k] - bf2f(hb));
  }
  *(u16x8*)(xh + 8 * i) = h;
  *(u16x8*)(xl + 8 * i) = lo;
}

// ---------- W_eff = W_base + B diag(c) A, split into hi/lo bf16 ----------
// grid: OUT_F*4 blocks of 256 threads; block handles one o-row, 1024 i's (4/thread)
__global__ void merge_w_kernel(const float* __restrict__ Wb,
                               const float* __restrict__ A,
                               const float* __restrict__ Bm,
                               const float* __restrict__ alphas,
                               const float* __restrict__ scalings,
                               uint16_t* __restrict__ wh,
                               uint16_t* __restrict__ wl) {
  const int o = blockIdx.x >> 2;
  const int i0 = ((blockIdx.x & 3) << 10) | (threadIdx.x << 2);
  __shared__ float brow[TOTAL_R];
  if (threadIdx.x < TOTAL_R) {
    int r = threadIdx.x;
    int s = seg_of(r);
    brow[r] = Bm[(size_t)o * TOTAL_R + r] * alphas[s] * scalings[s];
  }
  __syncthreads();
  const size_t base = (size_t)o * IN_F + i0;
  f32x4 acc = *(const f32x4*)(Wb + base);
#pragma unroll 7
  for (int r = 0; r < TOTAL_R; ++r) {
    f32x4 a = *(const f32x4*)(A + (size_t)r * IN_F + i0);
    acc += brow[r] * a;
  }
  u16x4 h, lo;
#pragma unroll
  for (int k = 0; k < 4; ++k) {
    uint16_t hb = f2bf_rn(acc[k]);
    h[k] = hb;
    lo[k] = f2bf_rn(acc[k] - bf2f(hb));
  }
  *(u16x4*)(wh + base) = h;
  *(u16x4*)(wl + base) = lo;
}

// ---------- split-bf16 GEMM: out = xh@wh^T + xh@wl^T + xl@wh^T + bias ----------
// m97 structure: 128x128 tile, BK=32, 256 threads (4 waves, 2x2), 16x16x32 MFMA
__global__ void gemm_split_bf16(const uint16_t* __restrict__ xh,
                                const uint16_t* __restrict__ xl,
                                const uint16_t* __restrict__ wh,
                                const uint16_t* __restrict__ wl,
                                const float* __restrict__ bias,
                                float* __restrict__ out) {
  __shared__ uint16_t sA[128 * 32];
  __shared__ uint16_t sB[128 * 32];
  const int t = threadIdx.x;
  const int l = t & 63;
  const int w = t >> 6;
  const int wr = w >> 1, wc = w & 1;
  const int lr = l & 15, lg = l >> 4;

  // bijective XCD swizzle (nwg = 2048 divisible by 8)
  const int nwg = 2048, cpx = nwg / 8;
  int swz = (blockIdx.x & 7) * cpx + (blockIdx.x >> 3);
  const int NBN = OUT_F / 128;  // 32
  const int bm = swz / NBN;
  const int bn = swz % NBN;
  const size_t brow = (size_t)bm * 128;
  const size_t bcol = (size_t)bn * 128;

  // staging map: thread t covers row sr (and sr+64), 8 cols at sc
  const int sr = t >> 2;
  const int sc = (t & 3) * 8;

  const uint16_t* Asrc[3] = {xh, xh, xl};
  const uint16_t* Bsrc[3] = {wh, wl, wh};

  f32x4 acc[4][4] = {};

  for (int seg = 0; seg < 3; ++seg) {
    const uint16_t* Ab = Asrc[seg] + (brow + sr) * (size_t)IN_F + sc;
    const uint16_t* Bb = Bsrc[seg] + (bcol + sr) * (size_t)IN_F + sc;
    for (int kt = 0; kt < IN_F / 32; ++kt) {
      const int k0 = kt * 32;
      gload_lds16(Ab + k0,                 &sA[t * 8]);
      gload_lds16(Ab + 64 * IN_F + k0,     &sA[t * 8 + 2048]);
      gload_lds16(Bb + k0,                 &sB[t * 8]);
      gload_lds16(Bb + 64 * IN_F + k0,     &sB[t * 8 + 2048]);
      __syncthreads();  // compiler drains vmcnt before barrier
      bf16x8 af[4], bfr[4];
#pragma unroll
      for (int i = 0; i < 4; ++i)
        af[i] = *(const bf16x8*)&sA[(wr * 64 + i * 16 + lr) * 32 + lg * 8];
#pragma unroll
      for (int j = 0; j < 4; ++j)
        bfr[j] = *(const bf16x8*)&sB[(wc * 64 + j * 16 + lr) * 32 + lg * 8];
#pragma unroll
      for (int i = 0; i < 4; ++i)
#pragma unroll
        for (int j = 0; j < 4; ++j)
          acc[i][j] = __builtin_amdgcn_mfma_f32_16x16x32_bf16(af[i], bfr[j], acc[i][j], 0, 0, 0);
      __syncthreads();  // all reads done before next-tile overwrite
    }
  }

  // epilogue: D layout col = lane&15, row = (lane>>4)*4 + reg
#pragma unroll
  for (int j = 0; j < 4; ++j) {
    const size_t col = bcol + wc * 64 + j * 16 + lr;
    const float bs = bias[col];
#pragma unroll
    for (int i = 0; i < 4; ++i) {
      const size_t row0 = brow + wr * 64 + i * 16 + lg * 4;
#pragma unroll
      for (int r = 0; r < 4; ++r)
        out[(row0 + r) * OUT_F + col] = acc[i][j][r] + bs;
    }
  }
}

// ================= fallback path (small workspace): fp32 =================

// z[m][r] = c[r] * dot(x[m], A[r])
__global__ __launch_bounds__(256) void fb_z_kernel(const float* __restrict__ x,
                                                   const float* __restrict__ A,
                                                   const float* __restrict__ alphas,
                                                   const float* __restrict__ scalings,
                                                   float* __restrict__ z) {
  __shared__ float sx[IN_F];
  __shared__ float red[256];
  const int m = blockIdx.x, t = threadIdx.x;
  for (int i = t; i < IN_F / 4; i += 256)
    ((float4*)sx)[i] = ((const float4*)(x + (size_t)m * IN_F))[i];
  __syncthreads();
  const int r = t >> 2, q = t & 3;
  float part = 0.f;
  if (r < TOTAL_R) {
    const float4* Ar = (const float4*)(A + (size_t)r * IN_F + q * 1024);
    const float4* xs = (const float4*)(sx + q * 1024);
    for (int k = 0; k < 256; ++k) {
      float4 av = Ar[k], xv = xs[k];
      part += av.x * xv.x + av.y * xv.y + av.z * xv.z + av.w * xv.w;
    }
  }
  red[t] = part;
  __syncthreads();
  if (q == 0 && r < TOTAL_R) {
    int s = seg_of(r);
    z[(size_t)m * TOTAL_R + r] =
        alphas[s] * scalings[s] * (red[t] + red[t + 1] + red[t + 2] + red[t + 3]);
  }
}

// out[m][o] = bias[o] + dot(x[m], Wb[o]) + dot63(z[m], Bm[o])
__global__ __launch_bounds__(256) void fb_gemm_fp32(const float* __restrict__ x,
                                                    const float* __restrict__ Wb,
                                                    const float* __restrict__ bb,
                                                    const float* __restrict__ Bm,
                                                    const float* __restrict__ z,
                                                    float* __restrict__ out) {
  __shared__ float sx[64][33];
  __shared__ float sw[64][33];
  const int t = threadIdx.x;
  const int tr = t >> 4, tc = t & 15;
  const int bm = blockIdx.x / (OUT_F / 64);
  const int bn = blockIdx.x % (OUT_F / 64);
  const size_t brow = (size_t)bm * 64, bcol = (size_t)bn * 64;
  const int r = t >> 2, c0 = (t & 3) * 8;
  float acc[4][4] = {};
  for (int k0 = 0; k0 < IN_F; k0 += 32) {
    float4 a0 = *(const float4*)(x + (brow + r) * IN_F + k0 + c0);
    float4 a1 = *(const float4*)(x + (brow + r) * IN_F + k0 + c0 + 4);
    float4 w0 = *(const float4*)(Wb + (bcol + r) * IN_F + k0 + c0);
    float4 w1 = *(const float4*)(Wb + (bcol + r) * IN_F + k0 + c0 + 4);
    __syncthreads();
    sx[r][c0 + 0] = a0.x; sx[r][c0 + 1] = a0.y; sx[r][c0 + 2] = a0.z; sx[r][c0 + 3] = a0.w;
    sx[r][c0 + 4] = a1.x; sx[r][c0 + 5] = a1.y; sx[r][c0 + 6] = a1.z; sx[r][c0 + 7] = a1.w;
    sw[r][c0 + 0] = w0.x; sw[r][c0 + 1] = w0.y; sw[r][c0 + 2] = w0.z; sw[r][c0 + 3] = w0.w;
    sw[r][c0 + 4] = w1.x; sw[r][c0 + 5] = w1.y; sw[r][c0 + 6] = w1.z; sw[r][c0 + 7] = w1.w;
    __syncthreads();
#pragma unroll
    for (int k = 0; k < 32; ++k) {
      float xa[4], wv[4];
#pragma unroll
      for (int i = 0; i < 4; ++i) xa[i] = sx[tr + 16 * i][k];
#pragma unroll
      for (int j = 0; j < 4; ++j) wv[j] = sw[tc + 16 * j][k];
#pragma unroll
      for (int i = 0; i < 4; ++i)
#pragma unroll
        for (int j = 0; j < 4; ++j) acc[i][j] += xa[i] * wv[j];
    }
  }
  // adapter epilogue straight from global (z ~2MB, B ~1MB -> L2-hot)
#pragma unroll 1
  for (int rr = 0; rr < TOTAL_R; ++rr) {
    float zr[4], br[4];
#pragma unroll
    for (int i = 0; i < 4; ++i) zr[i] = z[(brow + tr + 16 * i) * TOTAL_R + rr];
#pragma unroll
    for (int j = 0; j < 4; ++j) br[j] = Bm[(bcol + tc + 16 * j) * TOTAL_R + rr];
#pragma unroll
    for (int i = 0; i < 4; ++i)
#pragma unroll
      for (int j = 0; j < 4; ++j) acc[i][j] += zr[i] * br[j];
  }
#pragma unroll
  for (int i = 0; i < 4; ++i)
#pragma unroll
    for (int j = 0; j < 4; ++j) {
      size_t row = brow + tr + 16 * i, col = bcol + tc + 16 * j;
      out[row * OUT_F + col] = acc[i][j] + bb[col];
    }
}

extern "C" void kernel_launch(void* const* d_in, const int* in_sizes, int n_in,
                              void* d_out, int out_size, void* d_ws, size_t ws_size,
                              hipStream_t stream) {
  const float* x  = (const float*)d_in[0];
  const float* Wb = (const float*)d_in[1];
  const float* bb = (const float*)d_in[2];
  const float* A  = (const float*)d_in[3];
  const float* Bm = (const float*)d_in[4];
  const float* al = (const float*)d_in[5];
  const float* sc = (const float*)d_in[6];
  float* out = (float*)d_out;

  const size_t MB = (size_t)1 << 20;
  if (ws_size >= 192 * MB) {
    char* ws = (char*)d_ws;
    uint16_t* xh = (uint16_t*)(ws);
    uint16_t* xl = (uint16_t*)(ws + 64 * MB);
    uint16_t* wh = (uint16_t*)(ws + 128 * MB);
    uint16_t* wl = (uint16_t*)(ws + 160 * MB);
    split_x_kernel<<<(M_TOT * IN_F / 8) / 256, 256, 0, stream>>>(x, xh, xl);
    merge_w_kernel<<<OUT_F * 4, 256, 0, stream>>>(Wb, A, Bm, al, sc, wh, wl);
    gemm_split_bf16<<<2048, 256, 0, stream>>>(xh, xl, wh, wl, bb, out);
  } else {
    float* z = (float*)d_ws;  // needs 8192*63*4 ~= 2 MB
    fb_z_kernel<<<M_TOT, 256, 0, stream>>>(x, A, al, sc, z);
    fb_gemm_fp32<<<(M_TOT / 64) * (OUT_F / 64), 256, 0, stream>>>(x, Wb, bb, Bm, z, out);
  }
}

// Round 2
// 954.178 us; speedup vs baseline: 1.5348x; 1.5348x over previous
//
#include <hip/hip_runtime.h>
#include <cstdint>

#define IN_F 4096
#define OUT_F 4096
#define M_TOT 8192     // BATCH*SEQ = 4*2048
#define TOTAL_R 63

typedef __attribute__((ext_vector_type(8))) short bf16x8;
typedef __attribute__((ext_vector_type(4))) float f32x4;
typedef __attribute__((ext_vector_type(8))) unsigned short u16x8;
typedef __attribute__((ext_vector_type(4))) unsigned short u16x4;

__device__ __forceinline__ uint16_t f2bf_rn(float f) {
  uint32_t u = __float_as_uint(f);
  u += 0x7fffu + ((u >> 16) & 1u);   // round-to-nearest-even
  return (uint16_t)(u >> 16);
}
__device__ __forceinline__ float bf2f(uint16_t b) {
  return __uint_as_float(((uint32_t)b) << 16);
}

__device__ __forceinline__ void gload_lds16(const void* g, void* l) {
  __builtin_amdgcn_global_load_lds((const __attribute__((address_space(1))) void*)g,
                                   (__attribute__((address_space(3))) void*)l,
                                   16, 0, 0);
}

__device__ __forceinline__ int seg_of(int r) {
  // RANKS = [32,16,8,4,2,1] -> prefix 32,48,56,60,62,63
  return (r < 32) ? 0 : (r < 48) ? 1 : (r < 56) ? 2 : (r < 60) ? 3 : (r < 62) ? 4 : 5;
}

// ---------- split x (f32) into hi/lo bf16 ----------
__global__ void split_x_kernel(const float* __restrict__ x,
                               uint16_t* __restrict__ xh,
                               uint16_t* __restrict__ xl) {
  size_t i = (size_t)blockIdx.x * blockDim.x + threadIdx.x;  // one per 8 floats
  const float4* xv = (const float4*)x;
  float4 v0 = xv[2 * i];
  float4 v1 = xv[2 * i + 1];
  float v[8] = {v0.x, v0.y, v0.z, v0.w, v1.x, v1.y, v1.z, v1.w};
  u16x8 h, lo;
#pragma unroll
  for (int k = 0; k < 8; ++k) {
    uint16_t hb = f2bf_rn(v[k]);
    h[k] = hb;
    lo[k] = f2bf_rn(v[k] - bf2f(hb));
  }
  *(u16x8*)(xh + 8 * i) = h;
  *(u16x8*)(xl + 8 * i) = lo;
}

// ---------- W_eff = W_base + B diag(c) A, split into hi/lo bf16 ----------
__global__ void merge_w_kernel(const float* __restrict__ Wb,
                               const float* __restrict__ A,
                               const float* __restrict__ Bm,
                               const float* __restrict__ alphas,
                               const float* __restrict__ scalings,
                               uint16_t* __restrict__ wh,
                               uint16_t* __restrict__ wl) {
  const int o = blockIdx.x >> 2;
  const int i0 = ((blockIdx.x & 3) << 10) | (threadIdx.x << 2);
  __shared__ float brow[TOTAL_R];
  if (threadIdx.x < TOTAL_R) {
    int r = threadIdx.x;
    int s = seg_of(r);
    brow[r] = Bm[(size_t)o * TOTAL_R + r] * alphas[s] * scalings[s];
  }
  __syncthreads();
  const size_t base = (size_t)o * IN_F + i0;
  f32x4 acc = *(const f32x4*)(Wb + base);
#pragma unroll 7
  for (int r = 0; r < TOTAL_R; ++r) {
    f32x4 a = *(const f32x4*)(A + (size_t)r * IN_F + i0);
    acc += brow[r] * a;
  }
  u16x4 h, lo;
#pragma unroll
  for (int k = 0; k < 4; ++k) {
    uint16_t hb = f2bf_rn(acc[k]);
    h[k] = hb;
    lo[k] = f2bf_rn(acc[k] - bf2f(hb));
  }
  *(u16x4*)(wh + base) = h;
  *(u16x4*)(wl + base) = lo;
}

// ---------- fused split-bf16 GEMM ----------
// out = xh@wh^T + xl@wh^T + xh@wl^T + bias
// 128x128 tile, BK=32, 256 threads (4 waves 2x2), 16x16x32 MFMA.
// LDS: 4 tiles of 128x32 bf16, each packed [64 lds-rows][64 elems]
// (two logical rows per 128B line, 8 x 16B slots) with slot swizzle
// s_phys = s_logical ^ (lds_row & 7). Swizzle applied on BOTH the
// global source address (gload_lds dest stays linear) and the read addr.
__global__ __launch_bounds__(256) void gemm_mrlora(
    const uint16_t* __restrict__ xh, const uint16_t* __restrict__ xl,
    const uint16_t* __restrict__ wh, const uint16_t* __restrict__ wl,
    const float* __restrict__ bias, float* __restrict__ out) {
  __shared__ uint16_t sXh[4096];
  __shared__ uint16_t sXl[4096];
  __shared__ uint16_t sWh[4096];
  __shared__ uint16_t sWl[4096];
  const int t = threadIdx.x;
  const int l = t & 63;
  const int w = t >> 6;
  const int wr = w >> 1, wc = w & 1;
  const int lr = l & 15, lg = l >> 4;

  // raster: XCD chunk (256 blocks) covers 8 bm x 32 bn, bm-minor so 8
  // consecutive blocks share one 4MB W-panel (L2), A-band 16MB stays in L3.
  const int xcd = blockIdx.x & 7;
  const int kk = blockIdx.x >> 3;       // 0..255
  const int bm = xcd * 8 + (kk & 7);    // 64 rows of blocks
  const int bn = kk >> 3;               // 32 cols of blocks
  const size_t brow = (size_t)bm * 128;
  const size_t bcol = (size_t)bn * 128;

  // staging map: thread t fills LDS 16B slot (lds_row = t>>3, s = t&7),
  // which holds global (row = lds_row*2 + (sp>>2), colbyte = (sp&3)*16),
  // sp = s ^ (lds_row & 7). Same for the +64-row half at +4096B.
  const int lrow = t >> 3;
  const int sp = (t & 7) ^ (lrow & 7);
  const int grow = lrow * 2 + (sp >> 2);
  const int gcol = (sp & 3) * 8;

  const uint16_t* Ah = xh + (brow + grow) * (size_t)IN_F + gcol;
  const uint16_t* Al = xl + (brow + grow) * (size_t)IN_F + gcol;
  const uint16_t* Bh = wh + (bcol + grow) * (size_t)IN_F + gcol;
  const uint16_t* Bl = wl + (bcol + grow) * (size_t)IN_F + gcol;

  // fragment read offsets (elements): logical (row ri, 8 elems at lg*8)
  // -> (ri>>1)*64 + ((((ri&1)<<2 | lg) ^ ((ri>>1)&7)) << 3)
  int aoff[4], boff[4];
#pragma unroll
  for (int i = 0; i < 4; ++i) {
    int ri = wr * 64 + i * 16 + lr;
    aoff[i] = (ri >> 1) * 64 + (((((ri & 1) << 2) | lg) ^ ((ri >> 1) & 7)) << 3);
    int rj = wc * 64 + i * 16 + lr;
    boff[i] = (rj >> 1) * 64 + (((((rj & 1) << 2) | lg) ^ ((rj >> 1) & 7)) << 3);
  }

  f32x4 acc[4][4] = {};

  for (int kt = 0; kt < IN_F / 32; ++kt) {
    const int k0 = kt * 32;
    gload_lds16(Ah + k0,              &sXh[t * 8]);
    gload_lds16(Ah + 64 * IN_F + k0,  &sXh[t * 8 + 2048]);
    gload_lds16(Al + k0,              &sXl[t * 8]);
    gload_lds16(Al + 64 * IN_F + k0,  &sXl[t * 8 + 2048]);
    gload_lds16(Bh + k0,              &sWh[t * 8]);
    gload_lds16(Bh + 64 * IN_F + k0,  &sWh[t * 8 + 2048]);
    gload_lds16(Bl + k0,              &sWl[t * 8]);
    gload_lds16(Bl + 64 * IN_F + k0,  &sWl[t * 8 + 2048]);
    __syncthreads();  // compiler drains vmcnt before barrier

    bf16x8 ah[4], bh[4], alf[4], blf[4];
#pragma unroll
    for (int i = 0; i < 4; ++i) ah[i] = *(const bf16x8*)&sXh[aoff[i]];
#pragma unroll
    for (int j = 0; j < 4; ++j) bh[j] = *(const bf16x8*)&sWh[boff[j]];
#pragma unroll
    for (int i = 0; i < 4; ++i)
#pragma unroll
      for (int j = 0; j < 4; ++j)
        acc[i][j] = __builtin_amdgcn_mfma_f32_16x16x32_bf16(ah[i], bh[j], acc[i][j], 0, 0, 0);
#pragma unroll
    for (int i = 0; i < 4; ++i) alf[i] = *(const bf16x8*)&sXl[aoff[i]];
#pragma unroll
    for (int i = 0; i < 4; ++i)
#pragma unroll
      for (int j = 0; j < 4; ++j)
        acc[i][j] = __builtin_amdgcn_mfma_f32_16x16x32_bf16(alf[i], bh[j], acc[i][j], 0, 0, 0);
#pragma unroll
    for (int j = 0; j < 4; ++j) blf[j] = *(const bf16x8*)&sWl[boff[j]];
#pragma unroll
    for (int i = 0; i < 4; ++i)
#pragma unroll
      for (int j = 0; j < 4; ++j)
        acc[i][j] = __builtin_amdgcn_mfma_f32_16x16x32_bf16(ah[i], blf[j], acc[i][j], 0, 0, 0);
    __syncthreads();  // reads done before next-tile overwrite
  }

  // epilogue: D layout col = lane&15, row = (lane>>4)*4 + reg
#pragma unroll
  for (int j = 0; j < 4; ++j) {
    const size_t col = bcol + wc * 64 + j * 16 + lr;
    const float bs = bias[col];
#pragma unroll
    for (int i = 0; i < 4; ++i) {
      const size_t row0 = brow + wr * 64 + i * 16 + lg * 4;
#pragma unroll
      for (int r = 0; r < 4; ++r)
        out[(row0 + r) * OUT_F + col] = acc[i][j][r] + bs;
    }
  }
}

// ================= fallback path (small workspace): fp32 =================

__global__ __launch_bounds__(256) void fb_z_kernel(const float* __restrict__ x,
                                                   const float* __restrict__ A,
                                                   const float* __restrict__ alphas,
                                                   const float* __restrict__ scalings,
                                                   float* __restrict__ z) {
  __shared__ float sx[IN_F];
  __shared__ float red[256];
  const int m = blockIdx.x, t = threadIdx.x;
  for (int i = t; i < IN_F / 4; i += 256)
    ((float4*)sx)[i] = ((const float4*)(x + (size_t)m * IN_F))[i];
  __syncthreads();
  const int r = t >> 2, q = t & 3;
  float part = 0.f;
  if (r < TOTAL_R) {
    const float4* Ar = (const float4*)(A + (size_t)r * IN_F + q * 1024);
    const float4* xs = (const float4*)(sx + q * 1024);
    for (int k = 0; k < 256; ++k) {
      float4 av = Ar[k], xv = xs[k];
      part += av.x * xv.x + av.y * xv.y + av.z * xv.z + av.w * xv.w;
    }
  }
  red[t] = part;
  __syncthreads();
  if (q == 0 && r < TOTAL_R) {
    int s = seg_of(r);
    z[(size_t)m * TOTAL_R + r] =
        alphas[s] * scalings[s] * (red[t] + red[t + 1] + red[t + 2] + red[t + 3]);
  }
}

__global__ __launch_bounds__(256) void fb_gemm_fp32(const float* __restrict__ x,
                                                    const float* __restrict__ Wb,
                                                    const float* __restrict__ bb,
                                                    const float* __restrict__ Bm,
                                                    const float* __restrict__ z,
                                                    float* __restrict__ out) {
  __shared__ float sx[64][33];
  __shared__ float sw[64][33];
  const int t = threadIdx.x;
  const int tr = t >> 4, tc = t & 15;
  const int bm = blockIdx.x / (OUT_F / 64);
  const int bn = blockIdx.x % (OUT_F / 64);
  const size_t brow = (size_t)bm * 64, bcol = (size_t)bn * 64;
  const int r = t >> 2, c0 = (t & 3) * 8;
  float acc[4][4] = {};
  for (int k0 = 0; k0 < IN_F; k0 += 32) {
    float4 a0 = *(const float4*)(x + (brow + r) * IN_F + k0 + c0);
    float4 a1 = *(const float4*)(x + (brow + r) * IN_F + k0 + c0 + 4);
    float4 w0 = *(const float4*)(Wb + (bcol + r) * IN_F + k0 + c0);
    float4 w1 = *(const float4*)(Wb + (bcol + r) * IN_F + k0 + c0 + 4);
    __syncthreads();
    sx[r][c0 + 0] = a0.x; sx[r][c0 + 1] = a0.y; sx[r][c0 + 2] = a0.z; sx[r][c0 + 3] = a0.w;
    sx[r][c0 + 4] = a1.x; sx[r][c0 + 5] = a1.y; sx[r][c0 + 6] = a1.z; sx[r][c0 + 7] = a1.w;
    sw[r][c0 + 0] = w0.x; sw[r][c0 + 1] = w0.y; sw[r][c0 + 2] = w0.z; sw[r][c0 + 3] = w0.w;
    sw[r][c0 + 4] = w1.x; sw[r][c0 + 5] = w1.y; sw[r][c0 + 6] = w1.z; sw[r][c0 + 7] = w1.w;
    __syncthreads();
#pragma unroll
    for (int k = 0; k < 32; ++k) {
      float xa[4], wv[4];
#pragma unroll
      for (int i = 0; i < 4; ++i) xa[i] = sx[tr + 16 * i][k];
#pragma unroll
      for (int j = 0; j < 4; ++j) wv[j] = sw[tc + 16 * j][k];
#pragma unroll
      for (int i = 0; i < 4; ++i)
#pragma unroll
        for (int j = 0; j < 4; ++j) acc[i][j] += xa[i] * wv[j];
    }
  }
#pragma unroll 1
  for (int rr = 0; rr < TOTAL_R; ++rr) {
    float zr[4], br[4];
#pragma unroll
    for (int i = 0; i < 4; ++i) zr[i] = z[(brow + tr + 16 * i) * TOTAL_R + rr];
#pragma unroll
    for (int j = 0; j < 4; ++j) br[j] = Bm[(bcol + tc + 16 * j) * TOTAL_R + rr];
#pragma unroll
    for (int i = 0; i < 4; ++i)
#pragma unroll
      for (int j = 0; j < 4; ++j) acc[i][j] += zr[i] * br[j];
  }
#pragma unroll
  for (int i = 0; i < 4; ++i)
#pragma unroll
    for (int j = 0; j < 4; ++j) {
      size_t row = brow + tr + 16 * i, col = bcol + tc + 16 * j;
      out[row * OUT_F + col] = acc[i][j] + bb[col];
    }
}

extern "C" void kernel_launch(void* const* d_in, const int* in_sizes, int n_in,
                              void* d_out, int out_size, void* d_ws, size_t ws_size,
                              hipStream_t stream) {
  const float* x  = (const float*)d_in[0];
  const float* Wb = (const float*)d_in[1];
  const float* bb = (const float*)d_in[2];
  const float* A  = (const float*)d_in[3];
  const float* Bm = (const float*)d_in[4];
  const float* al = (const float*)d_in[5];
  const float* sc = (const float*)d_in[6];
  float* out = (float*)d_out;

  const size_t MB = (size_t)1 << 20;
  if (ws_size >= 192 * MB) {
    char* ws = (char*)d_ws;
    uint16_t* xh = (uint16_t*)(ws);
    uint16_t* xl = (uint16_t*)(ws + 64 * MB);
    uint16_t* wh = (uint16_t*)(ws + 128 * MB);
    uint16_t* wl = (uint16_t*)(ws + 160 * MB);
    split_x_kernel<<<(M_TOT * IN_F / 8) / 256, 256, 0, stream>>>(x, xh, xl);
    merge_w_kernel<<<OUT_F * 4, 256, 0, stream>>>(Wb, A, Bm, al, sc, wh, wl);
    gemm_mrlora<<<2048, 256, 0, stream>>>(xh, xl, wh, wl, bb, out);
  } else {
    float* z = (float*)d_ws;  // needs 8192*63*4 ~= 2 MB
    fb_z_kernel<<<M_TOT, 256, 0, stream>>>(x, A, al, sc, z);
    fb_gemm_fp32<<<(M_TOT / 64) * (OUT_F / 64), 256, 0, stream>>>(x, Wb, bb, Bm, z, out);
  }
}